// Round 1
// baseline (444.730 us; speedup 1.0000x reference)
//
#include <hip/hip_runtime.h>
#include <math.h>

#define S_LEN 2048
#define DMODEL 768
#define NHEAD 12
#define DHEAD 64
#define WIN_N 129
#define HALF_W 64

// ---------------- fp32 tiled GEMM: C = A @ W + bias ----------------
#define BM 128
#define BN 64
#define BK 16
#define TM 8
#define TN 4
// 256 threads: 16 n-threads x 16 m-threads, each computes 8x4 outputs.

__global__ __launch_bounds__(256, 2)
void gemm_bias_kernel(const float* __restrict__ A, const float* __restrict__ W,
                      const float* __restrict__ bias, float* __restrict__ C,
                      int M, int N, int K) {
  // As transposed [k][m], +4 pad keeps float4 alignment (132*4B % 16 == 0)
  // and spreads the strided scalar writes across banks.
  __shared__ float As[BK][BM + 4];
  __shared__ float Bs[BK][BN + 4];
  const int tid = threadIdx.x;
  const int tn = tid & 15;   // n-group
  const int tm = tid >> 4;   // m-group
  const int m0 = blockIdx.y * BM;
  const int n0 = blockIdx.x * BN;

  float acc[TM][TN];
#pragma unroll
  for (int i = 0; i < TM; ++i)
#pragma unroll
    for (int j = 0; j < TN; ++j) acc[i][j] = 0.f;

  for (int k0 = 0; k0 < K; k0 += BK) {
    // A tile: 128 rows x 16 cols = 512 float4; 2 per thread, coalesced.
#pragma unroll
    for (int r = 0; r < 2; ++r) {
      int idx = tid + 256 * r;
      int m = idx >> 2, kq = idx & 3;
      float4 a4 = *(const float4*)(A + (size_t)(m0 + m) * K + (k0 + kq * 4));
      As[kq * 4 + 0][m] = a4.x;
      As[kq * 4 + 1][m] = a4.y;
      As[kq * 4 + 2][m] = a4.z;
      As[kq * 4 + 3][m] = a4.w;
    }
    {
      // B tile: 16 rows x 64 cols = 256 float4; 1 per thread, coalesced.
      int kk = tid >> 4, nq = tid & 15;
      *(float4*)(&Bs[kk][nq * 4]) =
          *(const float4*)(W + (size_t)(k0 + kk) * N + (n0 + nq * 4));
    }
    __syncthreads();
#pragma unroll
    for (int kk = 0; kk < BK; ++kk) {
      float a[TM], b[TN];
      *(float4*)(&a[0]) = *(const float4*)(&As[kk][tm * TM]);
      *(float4*)(&a[4]) = *(const float4*)(&As[kk][tm * TM + 4]);
      *(float4*)(&b[0]) = *(const float4*)(&Bs[kk][tn * TN]);
#pragma unroll
      for (int i = 0; i < TM; ++i)
#pragma unroll
        for (int j = 0; j < TN; ++j) acc[i][j] = fmaf(a[i], b[j], acc[i][j]);
    }
    __syncthreads();
  }

  float4 bv4 = *(const float4*)(bias + n0 + tn * TN);
#pragma unroll
  for (int i = 0; i < TM; ++i) {
    float4 o;
    o.x = acc[i][0] + bv4.x;
    o.y = acc[i][1] + bv4.y;
    o.z = acc[i][2] + bv4.z;
    o.w = acc[i][3] + bv4.w;
    *(float4*)(C + (size_t)(m0 + tm * TM + i) * N + (n0 + tn * TN)) = o;
  }
}

// ---------------- sliding-window attention (fp32) ----------------
#define TQ 16
#define WROWS (TQ - 1 + WIN_N)  // 144 K/V rows cover all windows of the tile
#define KPAD 68                 // pad 64->68: keeps 16B align, breaks bank aliasing

__global__ __launch_bounds__(256, 2)
void swattn_kernel(const float* __restrict__ qb, const float* __restrict__ kb,
                   const float* __restrict__ vb, float* __restrict__ ctx) {
  __shared__ float Ks[WROWS][KPAD];
  __shared__ float Vs[WROWS][DHEAD];           // PV reads are lane=d stride-1: no pad needed
  __shared__ float attnBuf[4][WIN_N + 3];      // per-wave; 132 floats keeps rows 16B-aligned

  const int tid = threadIdx.x;
  const int lane = tid & 63;
  const int wave = tid >> 6;
  const int s0 = blockIdx.x * TQ;
  const int h = blockIdx.y;

  // Stage K/V window rows [s0-64, s0+64+15], positions clamped (reference
  // clips indices then masks scores, so clamped rows are never *used* invalid).
  for (int i = tid; i < WROWS * 16; i += 256) {
    int r = i >> 4, d = (i & 15) * 4;
    int pos = s0 - HALF_W + r;
    pos = pos < 0 ? 0 : (pos > S_LEN - 1 ? S_LEN - 1 : pos);
    size_t g = (size_t)pos * DMODEL + h * DHEAD + d;
    *(float4*)(&Ks[r][d]) = *(const float4*)(kb + g);
    *(float4*)(&Vs[r][d]) = *(const float4*)(vb + g);
  }
  __syncthreads();

  // Each wave processes queries ql = wave, wave+4, ... (4 iterations, uniform).
  for (int ql = wave; ql < TQ; ql += 4) {
    const float* qrow = qb + (size_t)(s0 + ql) * DMODEL + h * DHEAD;
    float sa = 0.f, sb = 0.f, sc = 0.f;  // w = lane, w = 64+lane, w = 128 (uniform)
#pragma unroll
    for (int d4 = 0; d4 < 16; ++d4) {
      float4 q4 = *(const float4*)(qrow + d4 * 4);  // lane-uniform, L1-cached
      float4 k1 = *(const float4*)(&Ks[ql + lane][d4 * 4]);
      float4 k2 = *(const float4*)(&Ks[ql + 64 + lane][d4 * 4]);
      float4 k3 = *(const float4*)(&Ks[ql + 128][d4 * 4]);  // broadcast
      sa += q4.x * k1.x + q4.y * k1.y + q4.z * k1.z + q4.w * k1.w;
      sb += q4.x * k2.x + q4.y * k2.y + q4.z * k2.z + q4.w * k2.w;
      sc += q4.x * k3.x + q4.y * k3.y + q4.z * k3.z + q4.w * k3.w;
    }
    sa *= 0.125f; sb *= 0.125f; sc *= 0.125f;  // 1/sqrt(64)

    const int base = s0 + ql - HALF_W;
    if (base + lane < 0 || base + lane >= S_LEN) sa = -1e30f;
    if (base + 64 + lane >= S_LEN) sb = -1e30f;          // lower bound always ok
    if (base + 128 >= S_LEN) sc = -1e30f;                // uniform

    float m = fmaxf(sa, fmaxf(sb, sc));
#pragma unroll
    for (int off = 32; off > 0; off >>= 1) m = fmaxf(m, __shfl_xor(m, off, 64));
    float pa = __expf(sa - m);
    float pb = __expf(sb - m);
    float pc = __expf(sc - m);
    float sum = pa + pb + (lane == 0 ? pc : 0.f);  // pc is wave-uniform: count once
#pragma unroll
    for (int off = 32; off > 0; off >>= 1) sum += __shfl_xor(sum, off, 64);
    float inv = 1.f / sum;
    attnBuf[wave][lane] = pa * inv;
    attnBuf[wave][64 + lane] = pb * inv;
    if (lane == 0) attnBuf[wave][128] = pc * inv;
    __syncthreads();  // uniform: every wave runs exactly 4 iterations

    // PV: lane = d. attn reads are wave-uniform broadcasts; V reads stride-1.
    float c = 0.f;
#pragma unroll 4
    for (int w = 0; w < 128; w += 4) {
      float4 aw = *(const float4*)(&attnBuf[wave][w]);
      c = fmaf(aw.x, Vs[ql + w + 0][lane], c);
      c = fmaf(aw.y, Vs[ql + w + 1][lane], c);
      c = fmaf(aw.z, Vs[ql + w + 2][lane], c);
      c = fmaf(aw.w, Vs[ql + w + 3][lane], c);
    }
    c = fmaf(attnBuf[wave][128], Vs[ql + 128][lane], c);
    ctx[(size_t)(s0 + ql) * DMODEL + h * DHEAD + lane] = c;
    __syncthreads();
  }
}

// ---------------- launch ----------------
extern "C" void kernel_launch(void* const* d_in, const int* in_sizes, int n_in,
                              void* d_out, int out_size, void* d_ws, size_t ws_size,
                              hipStream_t stream) {
  const float* query = (const float*)d_in[0];
  const float* key   = (const float*)d_in[1];
  const float* value = (const float*)d_in[2];
  const float* Wq = (const float*)d_in[3];
  const float* bq = (const float*)d_in[4];
  const float* Wk = (const float*)d_in[5];
  const float* bk = (const float*)d_in[6];
  const float* Wv = (const float*)d_in[7];
  const float* bv = (const float*)d_in[8];
  const float* Wo = (const float*)d_in[9];
  const float* bo = (const float*)d_in[10];
  float* out = (float*)d_out;

  // Workspace: q, k, v, ctx buffers — 4 * 2048*768*4B = 25.2 MB.
  const size_t nelem = (size_t)S_LEN * DMODEL;
  float* qbuf = (float*)d_ws;
  float* kbuf = qbuf + nelem;
  float* vbuf = kbuf + nelem;
  float* cbuf = vbuf + nelem;

  dim3 gemm_grid(DMODEL / BN, S_LEN / BM);  // (12, 16) = 192 blocks
  gemm_bias_kernel<<<gemm_grid, 256, 0, stream>>>(query, Wq, bq, qbuf, S_LEN, DMODEL, DMODEL);
  gemm_bias_kernel<<<gemm_grid, 256, 0, stream>>>(key,   Wk, bk, kbuf, S_LEN, DMODEL, DMODEL);
  gemm_bias_kernel<<<gemm_grid, 256, 0, stream>>>(value, Wv, bv, vbuf, S_LEN, DMODEL, DMODEL);
  swattn_kernel<<<dim3(S_LEN / TQ, NHEAD), 256, 0, stream>>>(qbuf, kbuf, vbuf, cbuf);
  gemm_bias_kernel<<<gemm_grid, 256, 0, stream>>>(cbuf, Wo, bo, out, S_LEN, DMODEL, DMODEL);
}

// Round 2
// 177.890 us; speedup vs baseline: 2.5000x; 2.5000x over previous
//
#include <hip/hip_runtime.h>
#include <math.h>

#define S_LEN 2048
#define DM 768
#define NHEAD 12
#define DHEAD 64
#define WIN_N 129
#define HALF_W 64

typedef _Float16 half8 __attribute__((ext_vector_type(8)));
typedef _Float16 half4_t __attribute__((ext_vector_type(4)));
typedef float floatx4 __attribute__((ext_vector_type(4)));

// ---- async global->LDS, 16B per lane (dest = wave-uniform base + lane*16) ----
typedef const __attribute__((address_space(1))) unsigned int* gas_ptr;
typedef __attribute__((address_space(3))) unsigned int* las_ptr;
__device__ __forceinline__ void gld_lds16(const void* g, void* l) {
  __builtin_amdgcn_global_load_lds((gas_ptr)g, (las_ptr)l, 16, 0, 0);
}

// ---------------- convert fp32 -> f16 (activations), z picks tensor ----------------
__global__ __launch_bounds__(256)
void cvt_act_kernel(const float* __restrict__ s0, const float* __restrict__ s1,
                    const float* __restrict__ s2, _Float16* __restrict__ d0,
                    _Float16* __restrict__ d1, _Float16* __restrict__ d2, int n4) {
  int z = blockIdx.z;
  const float* s = z == 0 ? s0 : z == 1 ? s1 : s2;
  _Float16* d = z == 0 ? d0 : z == 1 ? d1 : d2;
  int i = blockIdx.x * 256 + threadIdx.x;
  if (i >= n4) return;
  float4 v = ((const float4*)s)[i];
  half4_t h = {(_Float16)v.x, (_Float16)v.y, (_Float16)v.z, (_Float16)v.w};
  ((half4_t*)d)[i] = h;
}

// ---------------- convert+transpose W[k][n] fp32 -> Wt[n][k] f16 ----------------
__global__ __launch_bounds__(256)
void cvt_wt_kernel(const float* __restrict__ W0, const float* __restrict__ W1,
                   const float* __restrict__ W2, const float* __restrict__ W3,
                   _Float16* __restrict__ T0, _Float16* __restrict__ T1,
                   _Float16* __restrict__ T2, _Float16* __restrict__ T3) {
  __shared__ float t[64][65];
  int z = blockIdx.z;
  const float* W = z == 0 ? W0 : z == 1 ? W1 : z == 2 ? W2 : W3;
  _Float16* T = z == 0 ? T0 : z == 1 ? T1 : z == 2 ? T2 : T3;
  int n0 = blockIdx.x * 64, k0 = blockIdx.y * 64;
  int tx = threadIdx.x & 15, ty = threadIdx.x >> 4;
#pragma unroll
  for (int i = 0; i < 4; ++i) {
    int row = ty + i * 16;
    float4 v = *(const float4*)(W + (size_t)(k0 + row) * DM + n0 + tx * 4);
    t[row][tx * 4 + 0] = v.x; t[row][tx * 4 + 1] = v.y;
    t[row][tx * 4 + 2] = v.z; t[row][tx * 4 + 3] = v.w;
  }
  __syncthreads();
#pragma unroll
  for (int i = 0; i < 4; ++i) {
    int nn = ty + i * 16, kk = tx * 4;
    half4_t h = {(_Float16)t[kk + 0][nn], (_Float16)t[kk + 1][nn],
                 (_Float16)t[kk + 2][nn], (_Float16)t[kk + 3][nn]};
    *(half4_t*)(T + (size_t)(n0 + nn) * DM + k0 + kk) = h;
  }
}

// ---------------- f16 MFMA GEMM: C_fp32 = A_f16 @ Wt_f16^T + bias ----------------
// A: [M][K] f16 row-major.  Wt: [N][K] f16 row-major (pre-transposed W).
// Tile 128x64, BK=64, 256 threads (4 waves), wave w computes rows [w*32,w*32+32).
// LDS rows are 128B (= all 32 banks); chunk slot j holds global chunk j^(row&7)
// so ds_read_b128 fragment reads are ≤2-way bank-aliased (free).
#define GBM 128
#define GBN 64
#define GBK 64

__global__ __launch_bounds__(256, 2)
void gemm_f16_kernel(const _Float16* __restrict__ A0, const _Float16* __restrict__ A1,
                     const _Float16* __restrict__ A2, const _Float16* __restrict__ W0,
                     const _Float16* __restrict__ W1, const _Float16* __restrict__ W2,
                     const float* __restrict__ b0, const float* __restrict__ b1,
                     const float* __restrict__ b2, float* __restrict__ C0,
                     float* __restrict__ C1, float* __restrict__ C2) {
  __shared__ __align__(16) _Float16 As[GBM * GBK];  // 16 KB
  __shared__ __align__(16) _Float16 Bs[GBN * GBK];  // 8 KB
  const int z = blockIdx.z;
  const _Float16* A = z == 0 ? A0 : z == 1 ? A1 : A2;
  const _Float16* Wt = z == 0 ? W0 : z == 1 ? W1 : W2;
  const float* bias = z == 0 ? b0 : z == 1 ? b1 : b2;
  float* C = z == 0 ? C0 : z == 1 ? C1 : C2;

  const int tid = threadIdx.x;
  const int lane = tid & 63;
  const int w = tid >> 6;
  const int lr = lane & 15;  // row-in-16 (A) / col (B,D)
  const int lq = lane >> 4;  // quad
  const int m0 = blockIdx.y * GBM;
  const int n0 = blockIdx.x * GBN;
  const int wb = tid & 192;  // w*64

  floatx4 acc[2][4] = {};

  for (int k0 = 0; k0 < DM; k0 += GBK) {
    __syncthreads();  // protect LDS from overwrite while prior iter still reading
    // stage A: 128 rows x 8 chunks = 1024 chunks of 16B, 4 insts/thread
#pragma unroll
    for (int i = 0; i < 4; ++i) {
      int c = i * 256 + tid;
      int m = c >> 3, j = c & 7;
      int jg = j ^ (m & 7);
      gld_lds16(A + (size_t)(m0 + m) * DM + k0 + jg * 8, &As[(i * 256 + wb) * 8]);
    }
    // stage B: 64 rows x 8 chunks = 512 chunks, 2 insts/thread
#pragma unroll
    for (int i = 0; i < 2; ++i) {
      int c = i * 256 + tid;
      int n = c >> 3, j = c & 7;
      int jg = j ^ (n & 7);
      gld_lds16(Wt + (size_t)(n0 + n) * DM + k0 + jg * 8, &Bs[(i * 256 + wb) * 8]);
    }
    __syncthreads();  // compiler drains vmcnt(0) here -> staged data visible

#pragma unroll
    for (int kh = 0; kh < 2; ++kh) {
      half8 af[2], bf[4];
#pragma unroll
      for (int mt = 0; mt < 2; ++mt) {
        int m = w * 32 + mt * 16 + lr;
        int j = (kh * 4 + lq) ^ (m & 7);
        af[mt] = *(const half8*)&As[m * GBK + j * 8];
      }
#pragma unroll
      for (int nt = 0; nt < 4; ++nt) {
        int n = nt * 16 + lr;
        int j = (kh * 4 + lq) ^ (n & 7);
        bf[nt] = *(const half8*)&Bs[n * GBK + j * 8];
      }
#pragma unroll
      for (int mt = 0; mt < 2; ++mt)
#pragma unroll
        for (int nt = 0; nt < 4; ++nt)
          acc[mt][nt] = __builtin_amdgcn_mfma_f32_16x16x32_f16(af[mt], bf[nt], acc[mt][nt], 0, 0, 0);
    }
  }

  // epilogue: D[row=(lane>>4)*4+r][col=lane&15]
#pragma unroll
  for (int mt = 0; mt < 2; ++mt) {
    int row = m0 + w * 32 + mt * 16 + lq * 4;
#pragma unroll
    for (int nt = 0; nt < 4; ++nt) {
      int col = n0 + nt * 16 + lr;
      float bv = bias[col];
#pragma unroll
      for (int r = 0; r < 4; ++r)
        C[(size_t)(row + r) * DM + col] = acc[mt][nt][r] + bv;
    }
  }
}

// ---------------- sliding-window attention (fp32 in, f16 ctx out) ----------------
#define TQ 16
#define WROWS (TQ - 1 + WIN_N)
#define KPAD 68

__global__ __launch_bounds__(256, 2)
void swattn_kernel(const float* __restrict__ qb, const float* __restrict__ kb,
                   const float* __restrict__ vb, _Float16* __restrict__ ctx) {
  __shared__ float Ks[WROWS][KPAD];
  __shared__ float Vs[WROWS][DHEAD];
  __shared__ float attnBuf[4][WIN_N + 3];

  const int tid = threadIdx.x;
  const int lane = tid & 63;
  const int wave = tid >> 6;
  const int s0 = blockIdx.x * TQ;
  const int h = blockIdx.y;

  for (int i = tid; i < WROWS * 16; i += 256) {
    int r = i >> 4, d = (i & 15) * 4;
    int pos = s0 - HALF_W + r;
    pos = pos < 0 ? 0 : (pos > S_LEN - 1 ? S_LEN - 1 : pos);
    size_t g = (size_t)pos * DM + h * DHEAD + d;
    *(float4*)(&Ks[r][d]) = *(const float4*)(kb + g);
    *(float4*)(&Vs[r][d]) = *(const float4*)(vb + g);
  }
  __syncthreads();

  for (int ql = wave; ql < TQ; ql += 4) {
    const float* qrow = qb + (size_t)(s0 + ql) * DM + h * DHEAD;
    float sa = 0.f, sb = 0.f, sc = 0.f;
#pragma unroll
    for (int d4 = 0; d4 < 16; ++d4) {
      float4 q4 = *(const float4*)(qrow + d4 * 4);
      float4 k1 = *(const float4*)(&Ks[ql + lane][d4 * 4]);
      float4 k2 = *(const float4*)(&Ks[ql + 64 + lane][d4 * 4]);
      float4 k3 = *(const float4*)(&Ks[ql + 128][d4 * 4]);
      sa += q4.x * k1.x + q4.y * k1.y + q4.z * k1.z + q4.w * k1.w;
      sb += q4.x * k2.x + q4.y * k2.y + q4.z * k2.z + q4.w * k2.w;
      sc += q4.x * k3.x + q4.y * k3.y + q4.z * k3.z + q4.w * k3.w;
    }
    sa *= 0.125f; sb *= 0.125f; sc *= 0.125f;

    const int base = s0 + ql - HALF_W;
    if (base + lane < 0 || base + lane >= S_LEN) sa = -1e30f;
    if (base + 64 + lane >= S_LEN) sb = -1e30f;
    if (base + 128 >= S_LEN) sc = -1e30f;

    float m = fmaxf(sa, fmaxf(sb, sc));
#pragma unroll
    for (int off = 32; off > 0; off >>= 1) m = fmaxf(m, __shfl_xor(m, off, 64));
    float pa = __expf(sa - m);
    float pb = __expf(sb - m);
    float pc = __expf(sc - m);
    float sum = pa + pb + (lane == 0 ? pc : 0.f);
#pragma unroll
    for (int off = 32; off > 0; off >>= 1) sum += __shfl_xor(sum, off, 64);
    float inv = 1.f / sum;
    attnBuf[wave][lane] = pa * inv;
    attnBuf[wave][64 + lane] = pb * inv;
    if (lane == 0) attnBuf[wave][128] = pc * inv;
    __syncthreads();

    float c = 0.f;
#pragma unroll 4
    for (int wofs = 0; wofs < 128; wofs += 4) {
      float4 aw = *(const float4*)(&attnBuf[wave][wofs]);
      c = fmaf(aw.x, Vs[ql + wofs + 0][lane], c);
      c = fmaf(aw.y, Vs[ql + wofs + 1][lane], c);
      c = fmaf(aw.z, Vs[ql + wofs + 2][lane], c);
      c = fmaf(aw.w, Vs[ql + wofs + 3][lane], c);
    }
    c = fmaf(attnBuf[wave][128], Vs[ql + 128][lane], c);
    ctx[(size_t)(s0 + ql) * DM + h * DHEAD + lane] = (_Float16)c;
    __syncthreads();
  }
}

// ---------------- launch ----------------
extern "C" void kernel_launch(void* const* d_in, const int* in_sizes, int n_in,
                              void* d_out, int out_size, void* d_ws, size_t ws_size,
                              hipStream_t stream) {
  const float* query = (const float*)d_in[0];
  const float* key   = (const float*)d_in[1];
  const float* value = (const float*)d_in[2];
  const float* Wq = (const float*)d_in[3];
  const float* bq = (const float*)d_in[4];
  const float* Wk = (const float*)d_in[5];
  const float* bk = (const float*)d_in[6];
  const float* Wv = (const float*)d_in[7];
  const float* bv = (const float*)d_in[8];
  const float* Wo = (const float*)d_in[9];
  const float* bo = (const float*)d_in[10];
  float* out = (float*)d_out;

  const size_t nel = (size_t)S_LEN * DM;  // 1.57M
  const size_t wel = (size_t)DM * DM;     // 0.59M
  // ws: q/k/v fp32 (18.9MB) + Aq/Ak/Av f16 (9.4MB) + 4x Wt f16 (4.7MB) = 33MB
  float* qf = (float*)d_ws;
  float* kf = qf + nel;
  float* vf = kf + nel;
  _Float16* Aq = (_Float16*)(vf + nel);
  _Float16* Ak = Aq + nel;
  _Float16* Av = Ak + nel;
  _Float16* Wtq = Av + nel;
  _Float16* Wtk = Wtq + wel;
  _Float16* Wtv = Wtk + wel;
  _Float16* Wto = Wtv + wel;
  _Float16* ctxh = Aq;  // Aq is dead after the QKV GEMM; reuse for f16 ctx

  cvt_wt_kernel<<<dim3(12, 12, 4), 256, 0, stream>>>(Wq, Wk, Wv, Wo, Wtq, Wtk, Wtv, Wto);
  cvt_act_kernel<<<dim3(1536, 1, 3), 256, 0, stream>>>(query, key, value, Aq, Ak, Av, (int)(nel / 4));
  gemm_f16_kernel<<<dim3(DM / GBN, S_LEN / GBM, 3), 256, 0, stream>>>(
      Aq, Ak, Av, Wtq, Wtk, Wtv, bq, bk, bv, qf, kf, vf);
  swattn_kernel<<<dim3(S_LEN / TQ, NHEAD), 256, 0, stream>>>(qf, kf, vf, ctxh);
  gemm_f16_kernel<<<dim3(DM / GBN, S_LEN / GBM, 1), 256, 0, stream>>>(
      ctxh, ctxh, ctxh, Wto, Wto, Wto, bo, bo, bo, out, out, out);
}

// Round 3
// 153.525 us; speedup vs baseline: 2.8968x; 1.1587x over previous
//
#include <hip/hip_runtime.h>
#include <math.h>

#define S_LEN 2048
#define DM 768
#define NHEAD 12
#define DHEAD 64
#define WIN_N 129
#define HALF_W 64

typedef _Float16 half8 __attribute__((ext_vector_type(8)));
typedef _Float16 half4_t __attribute__((ext_vector_type(4)));
typedef float floatx4 __attribute__((ext_vector_type(4)));

// ---- async global->LDS, 16B per lane (dest = wave-uniform base + lane*16) ----
typedef const __attribute__((address_space(1))) unsigned int* gas_ptr;
typedef __attribute__((address_space(3))) unsigned int* las_ptr;
__device__ __forceinline__ void gld_lds16(const void* g, void* l) {
  __builtin_amdgcn_global_load_lds((gas_ptr)g, (las_ptr)l, 16, 0, 0);
}

// ---------------- convert fp32 -> f16 (activations), z picks tensor ----------------
__global__ __launch_bounds__(256)
void cvt_act_kernel(const float* __restrict__ s0, const float* __restrict__ s1,
                    const float* __restrict__ s2, _Float16* __restrict__ d0,
                    _Float16* __restrict__ d1, _Float16* __restrict__ d2, int n4) {
  int z = blockIdx.z;
  const float* s = z == 0 ? s0 : z == 1 ? s1 : s2;
  _Float16* d = z == 0 ? d0 : z == 1 ? d1 : d2;
  int i = blockIdx.x * 256 + threadIdx.x;
  if (i >= n4) return;
  float4 v = ((const float4*)s)[i];
  half4_t h = {(_Float16)v.x, (_Float16)v.y, (_Float16)v.z, (_Float16)v.w};
  ((half4_t*)d)[i] = h;
}

// ---------------- convert+transpose W[k][n] fp32 -> Wt[n][k] f16 ----------------
__global__ __launch_bounds__(256)
void cvt_wt_kernel(const float* __restrict__ W0, const float* __restrict__ W1,
                   const float* __restrict__ W2, const float* __restrict__ W3,
                   _Float16* __restrict__ T0, _Float16* __restrict__ T1,
                   _Float16* __restrict__ T2, _Float16* __restrict__ T3) {
  __shared__ float t[64][65];
  int z = blockIdx.z;
  const float* W = z == 0 ? W0 : z == 1 ? W1 : z == 2 ? W2 : W3;
  _Float16* T = z == 0 ? T0 : z == 1 ? T1 : z == 2 ? T2 : T3;
  int n0 = blockIdx.x * 64, k0 = blockIdx.y * 64;
  int tx = threadIdx.x & 15, ty = threadIdx.x >> 4;
#pragma unroll
  for (int i = 0; i < 4; ++i) {
    int row = ty + i * 16;
    float4 v = *(const float4*)(W + (size_t)(k0 + row) * DM + n0 + tx * 4);
    t[row][tx * 4 + 0] = v.x; t[row][tx * 4 + 1] = v.y;
    t[row][tx * 4 + 2] = v.z; t[row][tx * 4 + 3] = v.w;
  }
  __syncthreads();
#pragma unroll
  for (int i = 0; i < 4; ++i) {
    int nn = ty + i * 16, kk = tx * 4;
    half4_t h = {(_Float16)t[kk + 0][nn], (_Float16)t[kk + 1][nn],
                 (_Float16)t[kk + 2][nn], (_Float16)t[kk + 3][nn]};
    *(half4_t*)(T + (size_t)(n0 + nn) * DM + k0 + kk) = h;
  }
}

// ---------------- f16 MFMA GEMM, 128x128 tile ----------------
// A: [M][K] f16 row-major.  Wt: [N][K] f16 row-major.  BK=64, 4 waves,
// wave w computes rows [w*32, w*32+32) x all 128 cols.  XOR chunk swizzle.
#define GBM 128
#define GBN 128
#define GBK 64

__global__ __launch_bounds__(256, 2)
void gemm_f16_kernel(const _Float16* __restrict__ A0, const _Float16* __restrict__ A1,
                     const _Float16* __restrict__ A2, const _Float16* __restrict__ W0,
                     const _Float16* __restrict__ W1, const _Float16* __restrict__ W2,
                     const float* __restrict__ b0, const float* __restrict__ b1,
                     const float* __restrict__ b2, _Float16* __restrict__ H0,
                     _Float16* __restrict__ H1, _Float16* __restrict__ H2,
                     float* __restrict__ Cf, int fp32_out) {
  __shared__ __align__(16) _Float16 As[GBM * GBK];  // 16 KB
  __shared__ __align__(16) _Float16 Bs[GBN * GBK];  // 16 KB
  const int z = blockIdx.z;
  const _Float16* A = z == 0 ? A0 : z == 1 ? A1 : A2;
  const _Float16* Wt = z == 0 ? W0 : z == 1 ? W1 : W2;
  const float* bias = z == 0 ? b0 : z == 1 ? b1 : b2;
  _Float16* H = z == 0 ? H0 : z == 1 ? H1 : H2;

  const int tid = threadIdx.x;
  const int lane = tid & 63;
  const int w = tid >> 6;
  const int lr = lane & 15;
  const int lq = lane >> 4;
  const int m0 = blockIdx.y * GBM;
  const int n0 = blockIdx.x * GBN;
  const int wb = tid & 192;  // w*64

  floatx4 acc[2][8] = {};

  for (int k0 = 0; k0 < DM; k0 += GBK) {
    __syncthreads();
#pragma unroll
    for (int i = 0; i < 4; ++i) {  // A: 1024 chunks
      int c = i * 256 + tid;
      int m = c >> 3, j = c & 7;
      int jg = j ^ (m & 7);
      gld_lds16(A + (size_t)(m0 + m) * DM + k0 + jg * 8, &As[(i * 256 + wb) * 8]);
    }
#pragma unroll
    for (int i = 0; i < 4; ++i) {  // B: 1024 chunks
      int c = i * 256 + tid;
      int n = c >> 3, j = c & 7;
      int jg = j ^ (n & 7);
      gld_lds16(Wt + (size_t)(n0 + n) * DM + k0 + jg * 8, &Bs[(i * 256 + wb) * 8]);
    }
    __syncthreads();

#pragma unroll
    for (int kh = 0; kh < 2; ++kh) {
      half8 af[2], bf[8];
#pragma unroll
      for (int mt = 0; mt < 2; ++mt) {
        int m = w * 32 + mt * 16 + lr;
        int j = (kh * 4 + lq) ^ (m & 7);
        af[mt] = *(const half8*)&As[m * GBK + j * 8];
      }
#pragma unroll
      for (int nt = 0; nt < 8; ++nt) {
        int n = nt * 16 + lr;
        int j = (kh * 4 + lq) ^ (n & 7);
        bf[nt] = *(const half8*)&Bs[n * GBK + j * 8];
      }
#pragma unroll
      for (int mt = 0; mt < 2; ++mt)
#pragma unroll
        for (int nt = 0; nt < 8; ++nt)
          acc[mt][nt] = __builtin_amdgcn_mfma_f32_16x16x32_f16(af[mt], bf[nt], acc[mt][nt], 0, 0, 0);
    }
  }

#pragma unroll
  for (int mt = 0; mt < 2; ++mt) {
    int row = m0 + w * 32 + mt * 16 + lq * 4;
#pragma unroll
    for (int nt = 0; nt < 8; ++nt) {
      int col = n0 + nt * 16 + lr;
      float bv = bias[col];
#pragma unroll
      for (int r = 0; r < 4; ++r) {
        float val = acc[mt][nt][r] + bv;
        if (fp32_out) Cf[(size_t)(row + r) * DM + col] = val;
        else H[(size_t)(row + r) * DM + col] = (_Float16)val;
      }
    }
  }
}

// ---------------- V transpose: vh[2048][768] f16 -> vt[768][2048] f16 ----------------
__global__ __launch_bounds__(256)
void vtrans_kernel(const _Float16* __restrict__ vh, _Float16* __restrict__ vt) {
  int s0t = blockIdx.x * 64, d0t = blockIdx.y * 64;
#pragma unroll
  for (int i = 0; i < 2; ++i) {
    int c = i * 256 + threadIdx.x;
    int r = c >> 3, cc = c & 7;
    half8 v = *(const half8*)(vh + (size_t)(s0t + r) * DM + d0t + cc * 8);
#pragma unroll
    for (int j = 0; j < 8; ++j)
      vt[(size_t)(d0t + cc * 8 + j) * S_LEN + s0t + r] = v[j];
  }
}

// ---------------- MFMA sliding-window attention ----------------
// Block = 32 queries x 1 head. Window rows 160 cover all queries' [-64,+64].
// QK^T: A=Q natural, B=K natural (both d-major). PV: A=P natural, B=Vt (pos-major).
#define ATQ 32
#define AR 160

__global__ __launch_bounds__(256, 2)
void swattn_mfma_kernel(const _Float16* __restrict__ qh, const _Float16* __restrict__ kh,
                        const _Float16* __restrict__ vt, _Float16* __restrict__ ctx) {
  __shared__ __align__(16) _Float16 Qs[ATQ][72];     // 4.5 KB
  __shared__ __align__(16) _Float16 Ks[AR][72];      // 22.5 KB
  __shared__ __align__(16) _Float16 Vt[DHEAD][168];  // 21 KB
  __shared__ float Sbuf[ATQ][161];                   // 20.1 KB
  __shared__ __align__(16) _Float16 Pbuf[ATQ][168];  // 10.5 KB

  const int tid = threadIdx.x;
  const int lane = tid & 63, w = tid >> 6;
  const int lr = lane & 15, lq = lane >> 4;
  const int s0 = blockIdx.x * ATQ;
  const int h = blockIdx.y;

  // ---- stage Q (256 16B chunks) ----
  {
    int r = tid >> 3, cc = tid & 7;
    half8 v = *(const half8*)(qh + (size_t)(s0 + r) * DM + h * DHEAD + cc * 8);
    *(half8*)(&Qs[r][cc * 8]) = v;
  }
  // ---- stage K (1280 chunks), rows = global pos s0-64+r, clamped (masked later) ----
#pragma unroll
  for (int i = 0; i < 5; ++i) {
    int c = i * 256 + tid;
    int r = c >> 3, cc = c & 7;
    int pos = s0 - HALF_W + r;
    pos = pos < 0 ? 0 : (pos > S_LEN - 1 ? S_LEN - 1 : pos);
    half8 v = *(const half8*)(kh + (size_t)pos * DM + h * DHEAD + cc * 8);
    *(half8*)(&Ks[r][cc * 8]) = v;
  }
  // ---- stage Vt (1280 chunks), cols clamped chunk-wise (finite garbage, P=0 there) ----
#pragma unroll
  for (int i = 0; i < 5; ++i) {
    int c = i * 256 + tid;
    int row = c / 20, cc = c % 20;
    int cb = s0 - HALF_W + cc * 8;
    cb = cb < 0 ? 0 : (cb > S_LEN - 8 ? S_LEN - 8 : cb);
    half8 v = *(const half8*)(vt + (size_t)(h * DHEAD + row) * S_LEN + cb);
    *(half8*)(&Vt[row][cc * 8]) = v;
  }
  __syncthreads();

  // ---- QK^T: 20 tiles (2 qt x 10 pt); wave w -> qt=w>>1, pt in [(w&1)*5, +5) ----
  {
    const int qt = w >> 1;
    const int ptb = (w & 1) * 5;
    half8 aq[2];
#pragma unroll
    for (int k2 = 0; k2 < 2; ++k2)
      aq[k2] = *(const half8*)(&Qs[qt * 16 + lr][k2 * 32 + lq * 8]);
#pragma unroll
    for (int i = 0; i < 5; ++i) {
      int pt = ptb + i;
      floatx4 acc = {};
#pragma unroll
      for (int k2 = 0; k2 < 2; ++k2) {
        half8 bk = *(const half8*)(&Ks[pt * 16 + lr][k2 * 32 + lq * 8]);
        acc = __builtin_amdgcn_mfma_f32_16x16x32_f16(aq[k2], bk, acc, 0, 0, 0);
      }
#pragma unroll
      for (int rr = 0; rr < 4; ++rr)
        Sbuf[qt * 16 + lq * 4 + rr][pt * 16 + lr] = acc[rr] * 0.125f;
    }
  }
  __syncthreads();

  // ---- masked softmax: 8 rows per wave; valid iff p in [q,q+128] && pos in [0,S) ----
#pragma unroll
  for (int i = 0; i < 8; ++i) {
    int q = w * 8 + i;
    int p0 = lane, p1 = 64 + lane, p2 = 128 + lane;
    int g0 = s0 - HALF_W + p0, g1 = s0 - HALF_W + p1, g2 = s0 - HALF_W + p2;
    bool ok0 = (p0 >= q) && (g0 >= 0);  // p0<=63 <= q+128 always; g0<S always
    bool ok1 = (p1 <= q + 128) && (g1 >= 0) && (g1 < S_LEN);  // p1>=64>=q always
    bool ok2 = (lane < 32) && (p2 <= q + 128) && (g2 < S_LEN);
    float sv0 = ok0 ? Sbuf[q][p0] : -1e30f;
    float sv1 = ok1 ? Sbuf[q][p1] : -1e30f;
    float sv2 = ok2 ? Sbuf[q][p2] : -1e30f;
    float mx = fmaxf(sv0, fmaxf(sv1, sv2));
#pragma unroll
    for (int off = 32; off > 0; off >>= 1) mx = fmaxf(mx, __shfl_xor(mx, off, 64));
    float e0 = __expf(sv0 - mx), e1 = __expf(sv1 - mx), e2 = __expf(sv2 - mx);
    float sum = e0 + e1 + e2;
#pragma unroll
    for (int off = 32; off > 0; off >>= 1) sum += __shfl_xor(sum, off, 64);
    float inv = 1.f / sum;
    Pbuf[q][p0] = (_Float16)(e0 * inv);
    Pbuf[q][p1] = (_Float16)(e1 * inv);
    if (lane < 32) Pbuf[q][p2] = (_Float16)(e2 * inv);
  }
  __syncthreads();

  // ---- PV: 8 tiles (2 qt x 4 dt); wave w -> qt=w>>1, dt = (w&1)*2 + {0,1} ----
  {
    const int qt = w >> 1;
    const int dt0 = (w & 1) * 2;
    floatx4 a0 = {}, a1 = {};
#pragma unroll
    for (int ks = 0; ks < 5; ++ks) {
      half8 ap = *(const half8*)(&Pbuf[qt * 16 + lr][ks * 32 + lq * 8]);
      half8 bv0 = *(const half8*)(&Vt[dt0 * 16 + lr][ks * 32 + lq * 8]);
      half8 bv1 = *(const half8*)(&Vt[(dt0 + 1) * 16 + lr][ks * 32 + lq * 8]);
      a0 = __builtin_amdgcn_mfma_f32_16x16x32_f16(ap, bv0, a0, 0, 0, 0);
      a1 = __builtin_amdgcn_mfma_f32_16x16x32_f16(ap, bv1, a1, 0, 0, 0);
    }
#pragma unroll
    for (int rr = 0; rr < 4; ++rr) {
      size_t row = (size_t)(s0 + qt * 16 + lq * 4 + rr) * DM + h * DHEAD;
      ctx[row + dt0 * 16 + lr] = (_Float16)a0[rr];
      ctx[row + (dt0 + 1) * 16 + lr] = (_Float16)a1[rr];
    }
  }
}

// ---------------- launch ----------------
extern "C" void kernel_launch(void* const* d_in, const int* in_sizes, int n_in,
                              void* d_out, int out_size, void* d_ws, size_t ws_size,
                              hipStream_t stream) {
  const float* query = (const float*)d_in[0];
  const float* key   = (const float*)d_in[1];
  const float* value = (const float*)d_in[2];
  const float* Wq = (const float*)d_in[3];
  const float* bq = (const float*)d_in[4];
  const float* Wk = (const float*)d_in[5];
  const float* bk = (const float*)d_in[6];
  const float* Wv = (const float*)d_in[7];
  const float* bv = (const float*)d_in[8];
  const float* Wo = (const float*)d_in[9];
  const float* bo = (const float*)d_in[10];
  float* out = (float*)d_out;

  const size_t nel = (size_t)S_LEN * DM;
  const size_t wel = (size_t)DM * DM;
  _Float16* Aq = (_Float16*)d_ws;
  _Float16* Ak = Aq + nel;
  _Float16* Av = Ak + nel;
  _Float16* Wtq = Av + nel;
  _Float16* Wtk = Wtq + wel;
  _Float16* Wtv = Wtk + wel;
  _Float16* Wto = Wtv + wel;
  _Float16* qh = Wto + wel;
  _Float16* khb = qh + nel;
  _Float16* vhb = khb + nel;
  _Float16* Vtg = Ak;   // Ak dead after QKV GEMM
  _Float16* ctxh = Aq;  // Aq dead after QKV GEMM

  cvt_wt_kernel<<<dim3(12, 12, 4), 256, 0, stream>>>(Wq, Wk, Wv, Wo, Wtq, Wtk, Wtv, Wto);
  cvt_act_kernel<<<dim3(1536, 1, 3), 256, 0, stream>>>(query, key, value, Aq, Ak, Av, (int)(nel / 4));
  gemm_f16_kernel<<<dim3(DM / GBN, S_LEN / GBM, 3), 256, 0, stream>>>(
      Aq, Ak, Av, Wtq, Wtk, Wtv, bq, bk, bv, qh, khb, vhb, nullptr, 0);
  vtrans_kernel<<<dim3(S_LEN / 64, DM / 64), 256, 0, stream>>>(vhb, Vtg);
  swattn_mfma_kernel<<<dim3(S_LEN / ATQ, NHEAD), 256, 0, stream>>>(qh, khb, Vtg, ctxh);
  gemm_f16_kernel<<<dim3(DM / GBN, S_LEN / GBM, 1), 256, 0, stream>>>(
      ctxh, ctxh, ctxh, Wto, Wto, Wto, bo, bo, bo, nullptr, nullptr, nullptr, out, 1);
}

// Round 4
// 144.896 us; speedup vs baseline: 3.0693x; 1.0595x over previous
//
#include <hip/hip_runtime.h>
#include <math.h>

#define S_LEN 2048
#define DM 768
#define NHEAD 12
#define DHEAD 64
#define HALF_W 64

typedef _Float16 half8 __attribute__((ext_vector_type(8)));
typedef _Float16 half4_t __attribute__((ext_vector_type(4)));
typedef float floatx4 __attribute__((ext_vector_type(4)));

// ---- async global->LDS, 16B per lane (dest = wave-uniform base + lane*16) ----
typedef const __attribute__((address_space(1))) unsigned int* gas_ptr;
typedef __attribute__((address_space(3))) unsigned int* las_ptr;
__device__ __forceinline__ void gld_lds16(const void* g, void* l) {
  __builtin_amdgcn_global_load_lds((gas_ptr)g, (las_ptr)l, 16, 0, 0);
}

// ---------------- prep: blocks 0..575 = weight cvt+transpose; 576..5183 = act cvt ----
__global__ __launch_bounds__(256)
void prep_kernel(const float* __restrict__ Wq, const float* __restrict__ Wk,
                 const float* __restrict__ Wv, const float* __restrict__ Wo,
                 _Float16* __restrict__ Tq, _Float16* __restrict__ Tk,
                 _Float16* __restrict__ Tv, _Float16* __restrict__ To,
                 const float* __restrict__ qs, const float* __restrict__ ks,
                 const float* __restrict__ vs, _Float16* __restrict__ Aq,
                 _Float16* __restrict__ Ak, _Float16* __restrict__ Av) {
  __shared__ float t[64][65];
  int b = blockIdx.x;
  if (b < 576) {
    int z = b / 144, rem = b % 144;
    const float* W = z == 0 ? Wq : z == 1 ? Wk : z == 2 ? Wv : Wo;
    _Float16* T = z == 0 ? Tq : z == 1 ? Tk : z == 2 ? Tv : To;
    int n0 = (rem % 12) * 64, k0 = (rem / 12) * 64;
    int tx = threadIdx.x & 15, ty = threadIdx.x >> 4;
#pragma unroll
    for (int i = 0; i < 4; ++i) {
      int row = ty + i * 16;
      float4 v = *(const float4*)(W + (size_t)(k0 + row) * DM + n0 + tx * 4);
      t[row][tx * 4 + 0] = v.x; t[row][tx * 4 + 1] = v.y;
      t[row][tx * 4 + 2] = v.z; t[row][tx * 4 + 3] = v.w;
    }
    __syncthreads();
#pragma unroll
    for (int i = 0; i < 4; ++i) {
      int nn = ty + i * 16, kk = tx * 4;
      half4_t h = {(_Float16)t[kk + 0][nn], (_Float16)t[kk + 1][nn],
                   (_Float16)t[kk + 2][nn], (_Float16)t[kk + 3][nn]};
      *(half4_t*)(T + (size_t)(n0 + nn) * DM + k0 + kk) = h;
    }
  } else {
    int i = b - 576;
    int z = i / 1536;
    const float* s = z == 0 ? qs : z == 1 ? ks : vs;
    _Float16* d = z == 0 ? Aq : z == 1 ? Ak : Av;
    int idx = (i % 1536) * 256 + threadIdx.x;
    float4 v = ((const float4*)s)[idx];
    half4_t h = {(_Float16)v.x, (_Float16)v.y, (_Float16)v.z, (_Float16)v.w};
    ((half4_t*)d)[idx] = h;
  }
}

// ---------------- f16 MFMA GEMM, 128x128 block, m97 wave shape ----------------
// 4 waves in 2x2; wave tile 64x64 = 4x4 acc of 16x16x32. BK=64, XOR chunk swizzle.
// out modes: fp32_out=1 -> Cf fp32; else z==2 -> Vt transposed f16; else H f16.
#define GBM 128
#define GBN 128
#define GBK 64

__global__ __launch_bounds__(256, 2)
void gemm_f16_kernel(const _Float16* __restrict__ A0, const _Float16* __restrict__ A1,
                     const _Float16* __restrict__ A2, const _Float16* __restrict__ W0,
                     const _Float16* __restrict__ W1, const _Float16* __restrict__ W2,
                     const float* __restrict__ b0, const float* __restrict__ b1,
                     const float* __restrict__ b2, _Float16* __restrict__ H0,
                     _Float16* __restrict__ H1, _Float16* __restrict__ Vt,
                     float* __restrict__ Cf, int fp32_out) {
  __shared__ __align__(16) _Float16 As[GBM * GBK];  // 16 KB
  __shared__ __align__(16) _Float16 Bs[GBN * GBK];  // 16 KB
  const int z = blockIdx.z;
  const _Float16* A = z == 0 ? A0 : z == 1 ? A1 : A2;
  const _Float16* Wt = z == 0 ? W0 : z == 1 ? W1 : W2;
  const float* bias = z == 0 ? b0 : z == 1 ? b1 : b2;

  const int tid = threadIdx.x;
  const int lane = tid & 63;
  const int w = tid >> 6;
  const int lr = lane & 15;
  const int lq = lane >> 4;
  const int wm = w >> 1, wn = w & 1;
  const int m0 = blockIdx.y * GBM;
  const int n0 = blockIdx.x * GBN;
  const int wb = tid & 192;

  floatx4 acc[4][4] = {};

  for (int k0 = 0; k0 < DM; k0 += GBK) {
    __syncthreads();
#pragma unroll
    for (int i = 0; i < 4; ++i) {  // A: 1024 chunks
      int c = i * 256 + tid;
      int m = c >> 3, j = c & 7;
      int jg = j ^ (m & 7);
      gld_lds16(A + (size_t)(m0 + m) * DM + k0 + jg * 8, &As[(i * 256 + wb) * 8]);
    }
#pragma unroll
    for (int i = 0; i < 4; ++i) {  // B: 1024 chunks
      int c = i * 256 + tid;
      int n = c >> 3, j = c & 7;
      int jg = j ^ (n & 7);
      gld_lds16(Wt + (size_t)(n0 + n) * DM + k0 + jg * 8, &Bs[(i * 256 + wb) * 8]);
    }
    __syncthreads();

#pragma unroll
    for (int kh = 0; kh < 2; ++kh) {
      half8 af[4], bf[4];
#pragma unroll
      for (int mt = 0; mt < 4; ++mt) {
        int m = wm * 64 + mt * 16 + lr;
        int j = (kh * 4 + lq) ^ (m & 7);
        af[mt] = *(const half8*)&As[m * GBK + j * 8];
      }
#pragma unroll
      for (int nt = 0; nt < 4; ++nt) {
        int n = wn * 64 + nt * 16 + lr;
        int j = (kh * 4 + lq) ^ (n & 7);
        bf[nt] = *(const half8*)&Bs[n * GBK + j * 8];
      }
#pragma unroll
      for (int mt = 0; mt < 4; ++mt)
#pragma unroll
        for (int nt = 0; nt < 4; ++nt)
          acc[mt][nt] = __builtin_amdgcn_mfma_f32_16x16x32_f16(af[mt], bf[nt], acc[mt][nt], 0, 0, 0);
    }
  }

#pragma unroll
  for (int mt = 0; mt < 4; ++mt) {
    int row0 = m0 + wm * 64 + mt * 16 + lq * 4;
#pragma unroll
    for (int nt = 0; nt < 4; ++nt) {
      int col = n0 + wn * 64 + nt * 16 + lr;
      float bv = bias[col];
      if (fp32_out) {
#pragma unroll
        for (int rr = 0; rr < 4; ++rr)
          Cf[(size_t)(row0 + rr) * DM + col] = acc[mt][nt][rr] + bv;
      } else if (z == 2) {
        // V projection: write V^T[d=col][s=row] directly (fused vtrans)
        half4_t o = {(_Float16)(acc[mt][nt][0] + bv), (_Float16)(acc[mt][nt][1] + bv),
                     (_Float16)(acc[mt][nt][2] + bv), (_Float16)(acc[mt][nt][3] + bv)};
        *(half4_t*)(Vt + (size_t)col * S_LEN + row0) = o;
      } else {
        _Float16* H = z == 0 ? H0 : H1;
#pragma unroll
        for (int rr = 0; rr < 4; ++rr)
          H[(size_t)(row0 + rr) * DM + col] = (_Float16)(acc[mt][nt][rr] + bv);
      }
    }
  }
}

// ---------------- MFMA sliding-window attention ----------------
// Block = 32 queries x 1 head; K/Vt cover positions [s0-64, s0+96) (160 rows/cols).
// All staging via global_load_lds 16B with XOR chunk swizzle (rows = 128B = 32 banks).
#define ATQ 32
#define AR 160
#define VTC 24  // Vt chunks per row (192 f16)

__global__ __launch_bounds__(256, 2)
void swattn_mfma_kernel(const _Float16* __restrict__ qh, const _Float16* __restrict__ kh,
                        const _Float16* __restrict__ vt, _Float16* __restrict__ ctx) {
  __shared__ __align__(16) _Float16 Qs[ATQ * DHEAD];       // 4 KB
  __shared__ __align__(16) _Float16 Ks[AR * DHEAD];        // 20 KB
  __shared__ __align__(16) _Float16 Vs[DHEAD * VTC * 8];   // 24 KB
  __shared__ float Sbuf[ATQ][161];                         // 20.1 KB
  __shared__ __align__(16) _Float16 Pbuf[ATQ][168];        // 10.5 KB  (total 78.6 KB)

  const int tid = threadIdx.x;
  const int lane = tid & 63, w = tid >> 6;
  const int lr = lane & 15, lq = lane >> 4;
  const int s0 = blockIdx.x * ATQ;
  const int h = blockIdx.y;
  const int wb = tid & 192;

  // ---- stage Q: 256 chunks ----
  {
    int r = tid >> 3, j = tid & 7;
    int jg = j ^ (r & 7);
    gld_lds16(qh + (size_t)(s0 + r) * DM + h * DHEAD + jg * 8, &Qs[wb * 8]);
  }
  // ---- stage K: 1280 chunks, pos clamped (masked later) ----
#pragma unroll
  for (int i = 0; i < 5; ++i) {
    int c = i * 256 + tid;
    int r = c >> 3, j = c & 7;
    int jg = j ^ (r & 7);
    int pos = s0 - HALF_W + r;
    pos = pos < 0 ? 0 : (pos > S_LEN - 1 ? S_LEN - 1 : pos);
    gld_lds16(kh + (size_t)pos * DM + h * DHEAD + jg * 8, &Ks[(i * 256 + wb) * 8]);
  }
  // ---- stage Vt: 1536 chunks ([64 d][24 chunks of 8 cols]), cols clamped ----
#pragma unroll
  for (int i = 0; i < 6; ++i) {
    int c = i * 256 + tid;
    int r = c / VTC, j = c % VTC;
    int jg = j ^ (r & 7);  // XOR within aligned groups of 8 chunks
    int cb = s0 - HALF_W + jg * 8;
    cb = cb < 0 ? 0 : (cb > S_LEN - 8 ? S_LEN - 8 : cb);
    gld_lds16(vt + (size_t)(h * DHEAD + r) * S_LEN + cb, &Vs[(i * 256 + wb) * 8]);
  }
  __syncthreads();

  // ---- QK^T: 2 qt x 10 pt tiles; wave w -> qt=w>>1, pt in [(w&1)*5, +5) ----
  {
    const int qt = w >> 1;
    const int ptb = (w & 1) * 5;
    half8 aq[2];
#pragma unroll
    for (int k2 = 0; k2 < 2; ++k2) {
      int r = qt * 16 + lr, j = (k2 * 4 + lq) ^ (r & 7);
      aq[k2] = *(const half8*)&Qs[r * DHEAD + j * 8];
    }
#pragma unroll
    for (int i = 0; i < 5; ++i) {
      int pt = ptb + i;
      floatx4 acc = {};
#pragma unroll
      for (int k2 = 0; k2 < 2; ++k2) {
        int r = pt * 16 + lr, j = (k2 * 4 + lq) ^ (r & 7);
        half8 bk = *(const half8*)&Ks[r * DHEAD + j * 8];
        acc = __builtin_amdgcn_mfma_f32_16x16x32_f16(aq[k2], bk, acc, 0, 0, 0);
      }
#pragma unroll
      for (int rr = 0; rr < 4; ++rr)
        Sbuf[qt * 16 + lq * 4 + rr][pt * 16 + lr] = acc[rr] * 0.125f;
    }
  }
  __syncthreads();

  // ---- masked softmax: 8 rows/wave; valid iff p-q in [0,128] && pos in [0,S) ----
#pragma unroll
  for (int i = 0; i < 8; ++i) {
    int q = w * 8 + i;
    int p0 = lane, p1 = 64 + lane, p2 = 128 + lane;
    int g0 = s0 - HALF_W + p0, g1 = s0 + lane, g2 = s0 + HALF_W + lane;
    bool ok0 = (p0 >= q) && (g0 >= 0);
    bool ok1 = (g1 < S_LEN);
    bool ok2 = (lane <= q) && (g2 < S_LEN);   // lane<=q => p2<=q+128 and p2<160
    float sv0 = ok0 ? Sbuf[q][p0] : -1e30f;
    float sv1 = ok1 ? Sbuf[q][p1] : -1e30f;
    float sv2 = ok2 ? Sbuf[q][p2] : -1e30f;
    float mx = fmaxf(sv0, fmaxf(sv1, sv2));
#pragma unroll
    for (int off = 32; off > 0; off >>= 1) mx = fmaxf(mx, __shfl_xor(mx, off, 64));
    float e0 = __expf(sv0 - mx), e1 = __expf(sv1 - mx), e2 = __expf(sv2 - mx);
    float sum = e0 + e1 + e2;
#pragma unroll
    for (int off = 32; off > 0; off >>= 1) sum += __shfl_xor(sum, off, 64);
    float inv = 1.f / sum;
    Pbuf[q][p0] = (_Float16)(e0 * inv);
    Pbuf[q][p1] = (_Float16)(e1 * inv);
    if (lane < 32) Pbuf[q][p2] = (_Float16)(e2 * inv);  // p2 in [128,160)
  }
  __syncthreads();

  // ---- PV: 2 qt x 4 dt tiles; wave w -> qt=w>>1, dt = (w&1)*2 + {0,1} ----
  {
    const int qt = w >> 1;
    const int dt0 = (w & 1) * 2;
    floatx4 a0 = {}, a1 = {};
#pragma unroll
    for (int ks = 0; ks < 5; ++ks) {
      half8 ap = *(const half8*)&Pbuf[qt * 16 + lr][ks * 32 + lq * 8];
      int r0 = dt0 * 16 + lr, r1 = (dt0 + 1) * 16 + lr;
      int j0 = (ks * 4 + lq) ^ (r0 & 7), j1 = (ks * 4 + lq) ^ (r1 & 7);
      half8 bv0 = *(const half8*)&Vs[(r0 * VTC + j0) * 8];
      half8 bv1 = *(const half8*)&Vs[(r1 * VTC + j1) * 8];
      a0 = __builtin_amdgcn_mfma_f32_16x16x32_f16(ap, bv0, a0, 0, 0, 0);
      a1 = __builtin_amdgcn_mfma_f32_16x16x32_f16(ap, bv1, a1, 0, 0, 0);
    }
#pragma unroll
    for (int rr = 0; rr < 4; ++rr) {
      size_t row = (size_t)(s0 + qt * 16 + lq * 4 + rr) * DM + h * DHEAD;
      ctx[row + dt0 * 16 + lr] = (_Float16)a0[rr];
      ctx[row + (dt0 + 1) * 16 + lr] = (_Float16)a1[rr];
    }
  }
}

// ---------------- launch ----------------
extern "C" void kernel_launch(void* const* d_in, const int* in_sizes, int n_in,
                              void* d_out, int out_size, void* d_ws, size_t ws_size,
                              hipStream_t stream) {
  const float* query = (const float*)d_in[0];
  const float* key   = (const float*)d_in[1];
  const float* value = (const float*)d_in[2];
  const float* Wq = (const float*)d_in[3];
  const float* bq = (const float*)d_in[4];
  const float* Wk = (const float*)d_in[5];
  const float* bk = (const float*)d_in[6];
  const float* Wv = (const float*)d_in[7];
  const float* bv = (const float*)d_in[8];
  const float* Wo = (const float*)d_in[9];
  const float* bo = (const float*)d_in[10];
  float* out = (float*)d_out;

  const size_t nel = (size_t)S_LEN * DM;
  const size_t wel = (size_t)DM * DM;
  _Float16* Aq = (_Float16*)d_ws;
  _Float16* Ak = Aq + nel;
  _Float16* Av = Ak + nel;
  _Float16* Wtq = Av + nel;
  _Float16* Wtk = Wtq + wel;
  _Float16* Wtv = Wtk + wel;
  _Float16* Wto = Wtv + wel;
  _Float16* qh = Wto + wel;
  _Float16* khb = qh + nel;
  _Float16* Vtg = khb + nel;  // [768][2048] f16, written by gemm z=2 (do NOT alias A*)
  _Float16* ctxh = Aq;        // Aq dead after QKV GEMM

  prep_kernel<<<dim3(576 + 4608), 256, 0, stream>>>(
      Wq, Wk, Wv, Wo, Wtq, Wtk, Wtv, Wto, query, key, value, Aq, Ak, Av);
  gemm_f16_kernel<<<dim3(DM / GBN, S_LEN / GBM, 3), 256, 0, stream>>>(
      Aq, Ak, Av, Wtq, Wtk, Wtv, bq, bk, bv, qh, khb, Vtg, nullptr, 0);
  swattn_mfma_kernel<<<dim3(S_LEN / ATQ, NHEAD), 256, 0, stream>>>(qh, khb, Vtg, ctxh);
  gemm_f16_kernel<<<dim3(DM / GBN, S_LEN / GBM, 1), 256, 0, stream>>>(
      ctxh, ctxh, ctxh, Wto, Wto, Wto, bo, bo, bo, nullptr, nullptr, nullptr, out, 1);
}